// Round 1
// 156.347 us; speedup vs baseline: 1.0640x; 1.0640x over previous
//
#include <hip/hip_runtime.h>

#define BB 64
#define CC 64
#define TT 4000

// ---- gram (MFMA) geometry ----
#define SLABS 8              // blocks per batch; each block does 2 chunks of 250 t
#define TSLAB 250            // staged chunk, padded to 256 t (32 chunks of 8 bf16)
#define SLABT (2 * TSLAB)    // t span per block
#define GP_PITCH 264         // shorts per LDS row (16B-aligned rows, chunk 32 = pad)

// ---- apply geometry ----
#define TPB 128
#define NT2 ((TT + TPB - 1) / TPB)   // 32
#define XPITCH 132           // floats per xs row (16B aligned)
#define APITCH 72            // shorts per attL row (16B aligned)

// ws layout (floats): G_part[8][64][64][64] | S_part[8][64][64] | attB (bf16) [64][64][64]
#define GPART_ELEMS ((size_t)SLABS * BB * CC * CC)
#define SPART_ELEMS ((size_t)SLABS * BB * CC)

typedef short short8 __attribute__((ext_vector_type(8)));
typedef float f32x16 __attribute__((ext_vector_type(16)));

__device__ __forceinline__ short f2bf(float f) {
    unsigned u = __float_as_uint(f);
    u = (u + 0x7FFFu + ((u >> 16) & 1u)) >> 16;   // round-to-nearest-even
    return (short)u;
}
__device__ __forceinline__ float bfpair(unsigned u) {   // sum of 2 packed bf16
    return __uint_as_float(u << 16) + __uint_as_float(u & 0xFFFF0000u);
}

// G_part[s][b][r][c] = sum_{t in slab} x[b][r][t]*x[b][c][t]; S_part likewise.
// LDS chunk-XOR swizzle: 8-short chunk c of row r lives at chunk (c ^ (r&7)).
// 2 chunks of 250 t per block, K-accumulated in the MFMA accumulator.
__global__ __launch_bounds__(256)
void gram_mfma(const float* __restrict__ x, float* __restrict__ G_part,
               float* __restrict__ S_part) {
    __shared__ short xs[CC * GP_PITCH];   // 33.8 KB bf16
    __shared__ float sred[4 * 64];
    const int b    = blockIdx.x / SLABS;
    const int slab = blockIdx.x % SLABS;
    const int tid  = threadIdx.x;
    const int lane = tid & 63;
    const int wave = tid >> 6;
    const float* xb = x + (size_t)b * CC * TT;

    const int r0 = (wave >> 1) * 32, c0 = (wave & 1) * 32;
    const int m = lane & 31, half = lane >> 5;
    f32x16 acc;
    #pragma unroll
    for (int z = 0; z < 16; ++z) acc[z] = 0.f;
    float s_acc = 0.f;

    for (int ch = 0; ch < 2; ++ch) {
        const int t0 = slab * SLABT + ch * TSLAB;

        // stage fp32 -> bf16: issue 8 global float4 loads BEFORE any LDS write
        // (load-batched: keeps ~128B/thread in flight instead of 16B)
        #pragma unroll
        for (int g = 0; g < 2; ++g) {
            float4 v[8];
            #pragma unroll
            for (int k = 0; k < 8; ++k) {
                const int i = tid + 256 * (g * 8 + k);
                const int row = i >> 6, tq = i & 63;       // t_local = 4*tq
                float4 w = make_float4(0.f, 0.f, 0.f, 0.f);
                if (tq < 62) {
                    w = *(const float4*)(xb + row * TT + t0 + 4 * tq);
                } else if (tq == 62) {
                    const float* p = xb + row * TT + t0 + 248;
                    w.x = p[0]; w.y = p[1];
                }
                v[k] = w;
            }
            #pragma unroll
            for (int k = 0; k < 8; ++k) {
                const int i = tid + 256 * (g * 8 + k);
                const int row = i >> 6, tq = i & 63;
                short4 sv;
                sv.x = f2bf(v[k].x); sv.y = f2bf(v[k].y);
                sv.z = f2bf(v[k].z); sv.w = f2bf(v[k].w);
                const int pc = (tq >> 1) ^ (row & 7);      // swizzled chunk
                *(short4*)(xs + row * GP_PITCH + pc * 8 + (tq & 1) * 4) = sv;
            }
        }
        __syncthreads();

        // S partials: b64 reads (conflict-free under the swizzle), fp32 accumulate
        {
            const short* rowp = xs + lane * GP_PITCH;
            #pragma unroll
            for (int j = 0; j < 8; ++j) {
                const int pc = (wave * 8 + j) ^ (lane & 7);
                uint2 u0 = *(const uint2*)(rowp + pc * 8);
                uint2 u1 = *(const uint2*)(rowp + pc * 8 + 4);
                s_acc += bfpair(u0.x) + bfpair(u0.y) + bfpair(u1.x) + bfpair(u1.y);
            }
        }

        // MFMA: wave owns 32x32 tile (r0,c0); acc carries across both chunks
        #pragma unroll
        for (int ks = 0; ks < 16; ++ks) {
            const int ck = ks * 2 + half;                  // logical 8-short chunk of k
            short8 av = *(const short8*)(xs + (r0 + m) * GP_PITCH + (ck ^ (m & 7)) * 8);
            short8 bv = *(const short8*)(xs + (c0 + m) * GP_PITCH + (ck ^ (m & 7)) * 8);
            acc = __builtin_amdgcn_mfma_f32_32x32x16_bf16(av, bv, acc, 0, 0, 0);
        }
        __syncthreads();   // xs consumed; safe to restage next chunk
    }

    sred[wave * 64 + lane] = s_acc;
    __syncthreads();
    if (tid < 64) {
        float s = sred[tid] + sred[64 + tid] + sred[128 + tid] + sred[192 + tid];
        S_part[(slab * BB + b) * CC + tid] = s;
    }

    float* gp = G_part + ((size_t)slab * BB + b) * (CC * CC);
    #pragma unroll
    for (int r = 0; r < 16; ++r) {
        const int row = (r & 3) + 8 * (r >> 2) + 4 * half;
        gp[(r0 + row) * CC + (c0 + m)] = acc[r];
    }
}

// One block/batch: slab-reduce (float4-vectorized), energy, min-max norm, softmax.
// Emits attB[b][c][e] = bf16(P[e][c]) -- the A-operand layout apply_mfma wants,
// pre-rounded to bf16 (apply was doing this rounding anyway; halves the traffic).
__global__ __launch_bounds__(256)
void softmax_fused(const float* __restrict__ w1, const float* __restrict__ b1,
                   const float* __restrict__ w2, const float* __restrict__ b2,
                   const float* __restrict__ G_part, const float* __restrict__ S_part,
                   unsigned short* __restrict__ attB) {
    __shared__ float Es[64 * 65];
    __shared__ float Sb[64];
    __shared__ float red_mn[4 * 64], red_mx[4 * 64], red_sm[4 * 64];
    const int b   = blockIdx.x;
    const int tid = threadIdx.x;
    const int c = tid & 63, q = tid >> 6;

    // slab reduction: 16B loads, 8-deep unrolled -> 32 float4 in flight/thread
    #pragma unroll
    for (int j4 = 0; j4 < 4; ++j4) {
        const int jj = tid + 256 * j4;                      // 0..1023 (float4 index)
        float4 s = make_float4(0.f, 0.f, 0.f, 0.f);
        #pragma unroll
        for (int sl = 0; sl < SLABS; ++sl) {
            const float4 g = *(const float4*)(G_part + ((size_t)sl * BB + b) * 4096 + 4 * jj);
            s.x += g.x; s.y += g.y; s.z += g.z; s.w += g.w;
        }
        const int row = jj >> 4, col = (jj & 15) * 4;
        float* e = Es + row * 65 + col;
        e[0] = s.x; e[1] = s.y; e[2] = s.z; e[3] = s.w;
    }
    if (tid < 64) {
        float s = 0.f;
        #pragma unroll
        for (int sl = 0; sl < SLABS; ++sl)
            s += S_part[(sl * BB + b) * CC + tid];
        Sb[tid] = s;
    }
    float A = 0.f, Bc = 0.f, Be = 0.f, Cc = 0.f;
    #pragma unroll
    for (int j = 0; j < 8; ++j) {
        float a1 = w1[j], a2 = w2[j], q1 = b1[j], q2 = b2[j];
        A += a1 * a2; Bc += a1 * q2; Be += q1 * a2; Cc += q1 * q2;
    }
    Cc *= (float)TT;
    __syncthreads();

    const float sc = Sb[c];
    float ev[16], mn = 1e30f, mx = -1e30f;
    #pragma unroll
    for (int i = 0; i < 16; ++i) {
        const int e = 16 * q + i;
        float en = A * Es[c * 65 + e] + Bc * sc + Be * Sb[e] + Cc;
        ev[i] = en;
        mn = fminf(mn, en); mx = fmaxf(mx, en);
    }
    red_mn[q * 64 + c] = mn; red_mx[q * 64 + c] = mx;
    __syncthreads();
    mn = fminf(fminf(red_mn[c], red_mn[64 + c]), fminf(red_mn[128 + c], red_mn[192 + c]));
    mx = fmaxf(fmaxf(red_mx[c], red_mx[64 + c]), fmaxf(red_mx[128 + c], red_mx[192 + c]));
    const float ninv = 1.f / (mx - mn + 1e-8f);
    float pv[16], ls = 0.f;
    #pragma unroll
    for (int i = 0; i < 16; ++i) {
        float p = __expf((ev[i] - mn) * ninv);
        pv[i] = p; ls += p;
    }
    red_sm[q * 64 + c] = ls;
    __syncthreads();
    const float rinv = 1.f / (red_sm[c] + red_sm[64 + c] + red_sm[128 + c] + red_sm[192 + c]);
    #pragma unroll
    for (int i = 0; i < 16; ++i) Es[c * 65 + 16 * q + i] = pv[i] * rinv;   // Es[c][e]=P[c][e]
    __syncthreads();
    unsigned short* ab = attB + (size_t)b * 4096;
    #pragma unroll
    for (int j2 = tid; j2 < 2048; j2 += 256) {
        const int cc = j2 >> 5, e0 = (j2 & 31) * 2;        // attB[cc][ee] = bf16(P[ee][cc])
        const unsigned lo = (unsigned short)f2bf(Es[e0 * 65 + cc]);
        const unsigned hi = (unsigned short)f2bf(Es[(e0 + 1) * 65 + cc]);
        *(unsigned*)(ab + cc * 64 + e0) = lo | (hi << 16);
    }
}

// out[b,c,t] = gamma * sum_e P[e,c]*x[e,t] + x[b,c,t]  via bf16 MFMA.
// A = attB rows (bf16, staged straight into LDS), B-frags built from fp32 x tile.
__global__ __launch_bounds__(256)
void apply_mfma(const float* __restrict__ x, const unsigned short* __restrict__ attB,
                const float* __restrict__ gamma, float* __restrict__ out) {
    __shared__ float xs[CC * XPITCH];   // 33.8 KB fp32 [e][t]
    __shared__ short al[CC * APITCH];   // 9.2 KB bf16  [c][e]
    const int b  = blockIdx.x / NT2;
    const int t0 = (blockIdx.x % NT2) * TPB;
    const int tid = threadIdx.x;
    const int lane = tid & 63, wave = tid >> 6;
    const float* xb = x + (size_t)b * CC * TT;
    const unsigned short* ab = attB + (size_t)b * 4096;

    // attB loads issued first (independent, 16B each)
    short8 avv[2];
    #pragma unroll
    for (int k = 0; k < 2; ++k)
        avv[k] = *(const short8*)(ab + (tid + 256 * k) * 8);

    // x tile: load-batched groups of 4 float4 before the LDS writes
    #pragma unroll
    for (int g = 0; g < 2; ++g) {
        float4 v[4];
        #pragma unroll
        for (int k = 0; k < 4; ++k) {
            const int i = tid + 256 * (g * 4 + k);
            const int e = i >> 5, p = i & 31;
            const int t = t0 + 4 * p;
            v[k] = make_float4(0.f, 0.f, 0.f, 0.f);
            if (t < TT) v[k] = *(const float4*)(xb + e * TT + t);
        }
        #pragma unroll
        for (int k = 0; k < 4; ++k) {
            const int i = tid + 256 * (g * 4 + k);
            const int e = i >> 5, p = i & 31;
            *(float4*)(xs + e * XPITCH + 4 * p) = v[k];
        }
    }
    #pragma unroll
    for (int k = 0; k < 2; ++k) {
        const int i = tid + 256 * k;                       // 0..511 short8 chunks
        const int cch = i >> 3, q8 = i & 7;
        *(short8*)(al + cch * APITCH + q8 * 8) = avv[k];
    }
    __syncthreads();

    const int m = lane & 31, half = lane >> 5;
    const int c0 = (wave & 1) * 32;
    const int tb = (wave >> 1) * 64;
    f32x16 acc0, acc1;
    #pragma unroll
    for (int z = 0; z < 16; ++z) { acc0[z] = 0.f; acc1[z] = 0.f; }

    #pragma unroll
    for (int ks = 0; ks < 4; ++ks) {
        short8 av = *(const short8*)(al + (c0 + m) * APITCH + ks * 16 + 8 * half);
        const int eb = ks * 16 + 8 * half;
        short8 bv0, bv1;
        #pragma unroll
        for (int j = 0; j < 8; ++j) {
            bv0[j] = f2bf(xs[(eb + j) * XPITCH + tb + m]);
            bv1[j] = f2bf(xs[(eb + j) * XPITCH + tb + 32 + m]);
        }
        acc0 = __builtin_amdgcn_mfma_f32_32x32x16_bf16(av, bv0, acc0, 0, 0, 0);
        acc1 = __builtin_amdgcn_mfma_f32_32x32x16_bf16(av, bv1, acc1, 0, 0, 0);
    }

    const float gm = gamma[0];
    float* ob = out + (size_t)b * CC * TT;
    #pragma unroll
    for (int r = 0; r < 16; ++r) {
        const int row = (r & 3) + 8 * (r >> 2) + 4 * half;
        const int c = c0 + row;
        const int tl0 = tb + m, tl1 = tb + 32 + m;
        const int tg0 = t0 + tl0, tg1 = t0 + tl1;
        if (tg0 < TT) ob[c * TT + tg0] = gm * acc0[r] + xs[c * XPITCH + tl0];
        if (tg1 < TT) ob[c * TT + tg1] = gm * acc1[r] + xs[c * XPITCH + tl1];
    }
}

extern "C" void kernel_launch(void* const* d_in, const int* in_sizes, int n_in,
                              void* d_out, int out_size, void* d_ws, size_t ws_size,
                              hipStream_t stream) {
    const float* x  = (const float*)d_in[0];
    const float* w1 = (const float*)d_in[1];
    const float* b1 = (const float*)d_in[2];
    const float* w2 = (const float*)d_in[3];
    const float* b2 = (const float*)d_in[4];
    const float* gm = (const float*)d_in[5];
    float* out = (float*)d_out;

    float* G_part = (float*)d_ws;
    float* S_part = G_part + GPART_ELEMS;
    unsigned short* attB = (unsigned short*)(S_part + SPART_ELEMS);

    hipLaunchKernelGGL(gram_mfma, dim3(BB * SLABS), dim3(256), 0, stream,
                       x, G_part, S_part);
    hipLaunchKernelGGL(softmax_fused, dim3(BB), dim3(256), 0, stream,
                       w1, b1, w2, b2, G_part, S_part, attB);
    hipLaunchKernelGGL(apply_mfma, dim3(BB * NT2), dim3(256), 0, stream,
                       x, attB, gm, out);
}